// Round 8
// baseline (186.623 us; speedup 1.0000x reference)
//
#include <hip/hip_runtime.h>
#include <math.h>

typedef unsigned short u16;
typedef float f32x4 __attribute__((ext_vector_type(4)));
typedef __bf16 bf16x8 __attribute__((ext_vector_type(8)));

#define B_ 2
#define S_ 2048
#define D_ 768
#define H_ 12
#define DH_ 64

__device__ __forceinline__ u16 f2bf(float x) {
  union { float f; unsigned u; } v; v.f = x;
  unsigned r = v.u + 0x7fffu + ((v.u >> 16) & 1u);
  return (u16)(r >> 16);
}

__device__ __forceinline__ f32x4 zero4() { f32x4 z = {0.f, 0.f, 0.f, 0.f}; return z; }

__device__ __forceinline__ f32x4 mfma16(bf16x8 a, bf16x8 b, f32x4 c) {
  return __builtin_amdgcn_mfma_f32_16x16x32_bf16(a, b, c, 0, 0, 0);
}

__device__ __forceinline__ void gload_lds16(const void* g, void* l) {
  __builtin_amdgcn_global_load_lds((const __attribute__((address_space(1))) void*)g,
                                   (__attribute__((address_space(3))) void*)l, 16, 0, 0);
}

// ---------------- f32 -> bf16 conversion (hidden + 4 weights) ----------------
__global__ void cvt_kernel(const float* __restrict__ hid, const float* __restrict__ qw,
                           const float* __restrict__ kw, const float* __restrict__ vw,
                           const float* __restrict__ ow, u16* __restrict__ Hb,
                           u16* __restrict__ Wb) {
  const int NH = B_ * S_ * D_;      // 3145728
  const int NW = D_ * D_;           // 589824
  const int T4 = (NH + 4 * NW) >> 2;
  int stride = gridDim.x * blockDim.x;
  for (int i = blockIdx.x * blockDim.x + threadIdx.x; i < T4; i += stride) {
    int e = i << 2;
    const float* src; u16* dst;
    if (e < NH) { src = hid + e; dst = Hb + e; }
    else {
      int o = e - NH;
      int m = o / NW, oo = o - m * NW;
      src = (m == 0 ? qw : m == 1 ? kw : m == 2 ? vw : ow) + oo;
      dst = Wb + o;
    }
    f32x4 v = *(const f32x4*)src;
    uint2 o2;
    o2.x = (unsigned)f2bf(v[0]) | ((unsigned)f2bf(v[1]) << 16);
    o2.y = (unsigned)f2bf(v[2]) | ((unsigned)f2bf(v[3]) << 16);
    *(uint2*)dst = o2;
  }
}

// ---------------- bias prepack: pb = bf16(exp(bias)), attn-consumption order ----
// grid 6144 blocks x 256 thr; block = (h, qt, band) with band = 4 q-rows.
// Reads a CONTIGUOUS 32 KB f32 band (4 full bias rows) -> exp -> bf16 LDS ->
// writes 16 KB in per-thread chunks: chunk(h,qt,kt,w,lane) = 8 bf16 values
// [kf 0..1][r 0..3] that attn thread (w,lane) consumes at tile kt. All reads
// and writes are coalesced sequential runs (>=1 KB).
__global__ __launch_bounds__(256) void prepack_kernel(const float* __restrict__ bias,
                                                      u16* __restrict__ pb) {
  __shared__ __align__(16) u16 bl[4][2056];
  int x = blockIdx.x;
  int band = x & 15, qt = (x >> 4) & 31, h = x >> 9;
  int t = threadIdx.x;
  const float* src = bias + ((size_t)h * S_ + qt * 64 + band * 4) * S_;
#pragma unroll
  for (int p = 0; p < 8; ++p) {
    int e = p * 1024 + t * 4;
    f32x4 v = *(const f32x4*)(src + e);
    u16 a0 = f2bf(__expf(v[0])), a1 = f2bf(__expf(v[1]));
    u16 a2 = f2bf(__expf(v[2])), a3 = f2bf(__expf(v[3]));
    int row = e >> 11, col = e & 2047;
    uint2 pk;
    pk.x = (unsigned)a0 | ((unsigned)a1 << 16);
    pk.y = (unsigned)a2 | ((unsigned)a3 << 16);
    *(uint2*)&bl[row][col] = pk;
  }
  __syncthreads();
  int qg = band >> 2, l4 = band & 3;
  int w_ = t >> 6, lane_ = t & 63;
  size_t obase = ((size_t)h * 32 + qt) * 32 * 4096;   // u16 units; kt-block = 4096 u16
#pragma unroll
  for (int i = 0; i < 4; ++i) {
    int id = w_ * 256 + i * 64 + lane_;               // consecutive lanes -> consecutive chunks
    int kt = id >> 5, rem = id & 31;
    int kg = rem >> 4, l15 = rem & 15;
    u16 vals[8] __attribute__((aligned(16)));
#pragma unroll
    for (int kf = 0; kf < 2; ++kf)
#pragma unroll
      for (int r = 0; r < 4; ++r)
        vals[kf * 4 + r] = bl[r][kt * 64 + kg * 32 + kf * 16 + l15];
    int w = kg * 4 + qg, lane = l4 * 16 + l15;
    *(uint4*)(pb + obase + (size_t)kt * 4096 + (w * 64 + lane) * 8) = *(const uint4*)vals;
  }
}

// ---------------- GEMM: out = A @ W^T (+bias), m97 structure ----------------
#define BM 128
#define BN 128
#define BK 64

__global__ __launch_bounds__(256) void gemm_kernel(
    const u16* __restrict__ A, const u16* __restrict__ W,
    const float* __restrict__ bq, const float* __restrict__ bk, const float* __restrict__ bv,
    u16* __restrict__ Qb, u16* __restrict__ Kb, u16* __restrict__ Vtmp,
    float* __restrict__ Of, const float* __restrict__ bO, int mode)
{
  __shared__ __align__(16) u16 As[BM * BK];
  __shared__ __align__(16) u16 Bs[BN * BK];
  int t = threadIdx.x;
  int lane = t & 63, w = t >> 6;
  int wr = w >> 1, wc = w & 1;
  int l15 = lane & 15, l4 = lane >> 4;
  int m0 = blockIdx.y * BM, n0 = blockIdx.x * BN;

  f32x4 acc[4][4];
#pragma unroll
  for (int i = 0; i < 4; ++i)
#pragma unroll
    for (int j = 0; j < 4; ++j) acc[i][j] = zero4();

  const int K = D_;
  for (int k0 = 0; k0 < K; k0 += BK) {
    __syncthreads();
#pragma unroll
    for (int p = 0; p < 4; ++p) {
      int seg = p * 4 + w;
      int bd = seg * 64 + lane;
      int row = bd >> 3;
      int slot = (bd & 7) ^ (row & 7);
      gload_lds16(A + (size_t)(m0 + row) * K + k0 + slot * 8, (char*)As + seg * 1024);
      gload_lds16(W + (size_t)(n0 + row) * K + k0 + slot * 8, (char*)Bs + seg * 1024);
    }
    __syncthreads();
#pragma unroll
    for (int kk = 0; kk < 2; ++kk) {
      bf16x8 af[4], bfr[4];
#pragma unroll
      for (int i = 0; i < 4; ++i) {
        int ra = wr * 64 + i * 16 + l15;
        af[i] = *(const bf16x8*)((const char*)As + ra * 128 +
                                 ((kk * 64 + (l4 << 4)) ^ ((ra & 7) << 4)));
        int rb = wc * 64 + i * 16 + l15;
        bfr[i] = *(const bf16x8*)((const char*)Bs + rb * 128 +
                                  ((kk * 64 + (l4 << 4)) ^ ((rb & 7) << 4)));
      }
#pragma unroll
      for (int i = 0; i < 4; ++i)
#pragma unroll
        for (int j = 0; j < 4; ++j)
          acc[i][j] = mfma16(af[i], bfr[j], acc[i][j]);
    }
  }

  if (mode == 0) {
    int mat = n0 / D_;
    int ncol0 = (n0 - mat * D_) + wc * 64;
    const float* bias = (mat == 0) ? bq : (mat == 1 ? bk : bv);
    u16* outp = (mat == 0) ? Qb : (mat == 1 ? Kb : Vtmp);
    float scale = (mat == 0) ? 0.125f : 1.0f;
    int h = ncol0 >> 6;
#pragma unroll
    for (int j = 0; j < 4; ++j) {
      int d = j * 16 + l15;
      float bvv = bias[ncol0 + d];
#pragma unroll
      for (int i = 0; i < 4; ++i) {
#pragma unroll
        for (int r = 0; r < 4; ++r) {
          int m = m0 + wr * 64 + i * 16 + (l4 << 2) + r;
          int bb = m >> 11, ss = m & 2047;
          float val = (acc[i][j][r] + bvv) * scale;
          outp[(((size_t)bb * H_ + h) * S_ + ss) * DH_ + d] = f2bf(val);
        }
      }
    }
  } else {
#pragma unroll
    for (int j = 0; j < 4; ++j) {
      int n = n0 + wc * 64 + j * 16 + l15;
      float bvv = bO[n];
#pragma unroll
      for (int i = 0; i < 4; ++i) {
#pragma unroll
        for (int r = 0; r < 4; ++r) {
          int m = m0 + wr * 64 + i * 16 + (l4 << 2) + r;
          Of[(size_t)m * D_ + n] = acc[i][j][r] + bvv;
        }
      }
    }
  }
}

// ---------------- V transpose: [B,H,S,DH] -> [B,H,DH,S] ----------------
__global__ __launch_bounds__(256) void vtrans_kernel(const u16* __restrict__ V,
                                                     u16* __restrict__ Vt) {
  __shared__ __align__(16) u16 tile[64 * 64];
  int t = threadIdx.x;
  int s0 = blockIdx.x * 64;
  int bh = blockIdx.y;
  const u16* src = V + ((size_t)bh * S_ + s0) * DH_;
#pragma unroll
  for (int p = 0; p < 2; ++p) {
    int bd = t + p * 256;
    int row = bd >> 3, slot = bd & 7;
    uint4 v = *(const uint4*)(src + row * 64 + slot * 8);
    *(uint4*)((char*)tile + row * 128 + ((slot ^ (row & 7)) << 4)) = v;
  }
  __syncthreads();
  int d = t >> 2, sc = (t & 3) * 16;
  u16* dst = Vt + ((size_t)bh * DH_ + d) * S_ + s0 + sc;
  int colB = d * 2;
#pragma unroll
  for (int half = 0; half < 2; ++half) {
    u16 tmp[8] __attribute__((aligned(16)));
#pragma unroll
    for (int j = 0; j < 8; ++j) {
      int s = sc + half * 8 + j;
      tmp[j] = *(const u16*)((const char*)tile + s * 128 +
                             (((colB >> 4) ^ (s & 7)) << 4) + (colB & 15));
    }
    *(uint4*)(dst + half * 8) = *(const uint4*)tmp;
  }
}

// ---------------- flash attention: 8-wave split-KV + streamed exp(bias) ----
// grid (S/64, H, B), 512 threads = 8 waves; wave (qg=w&3, kg=w>>2) owns 16 q-rows
// x 32 kv-cols. Bias comes PRE-EXP'd and bf16-packed in per-thread order: one
// coalesced global_load_dwordx4 per thread per k-tile (8 KB/block, sequential
// across iters), register-consumed. p = exp(s + mask) * pb. Fixed-reference
// softmax; per-lane partial denominators; k-split partials combined in epilogue.
__global__ __launch_bounds__(512, 6) void attn_kernel(
    const u16* __restrict__ Qb, const u16* __restrict__ Kb, const u16* __restrict__ Vt,
    const u16* __restrict__ pb, const float* __restrict__ mask, u16* __restrict__ Cb)
{
  __shared__ __align__(16) u16 Ks[2][64 * 64];
  __shared__ __align__(16) u16 Vs[2][64 * 64];
  // union region: iter-phase Ps[4][16][72] u16 (9216 B) / epilogue-phase
  // Osh[4][16][66] f32 (16896 B) + Lsh[4][2][16] f32 (512 B) = 17408 B
  __shared__ __align__(16) char upool[17408];
  u16 (*Ps)[16][72] = (u16 (*)[16][72])upool;
  float (*Osh)[16][66] = (float (*)[16][66])upool;
  float (*Lsh)[2][16] = (float (*)[2][16])(upool + 16896);

  int t = threadIdx.x, lane = t & 63, w = t >> 6;
  int qg = w & 3, kg = w >> 2;
  int q0 = blockIdx.x * 64, h = blockIdx.y, b = blockIdx.z;
  size_t bh = (size_t)b * H_ + h;
  const u16* Qp = Qb + (bh * S_ + q0) * DH_;
  const u16* Kp = Kb + bh * S_ * DH_;
  const u16* Vp = Vt + bh * DH_ * S_;             // [64][2048]
  const float* maskp = mask + (size_t)b * S_;
  int l15 = lane & 15, l4 = lane >> 4;
  int kc0 = kg * 32;                               // this wave's kv-col base

  // per-thread pb stream: 16 B per k-tile, b-independent (L3 dedups batches)
  const u16* pbp = pb + ((size_t)h * 32 + blockIdx.x) * 32 * 4096 + (w * 64 + lane) * 8;

  // Q fragments (softmax scale pre-folded)
  bf16x8 qf0, qf1;
  {
    const u16* qrow = Qp + (qg * 16 + l15) * DH_;
    qf0 = *(const bf16x8*)(qrow + l4 * 8);
    qf1 = *(const bf16x8*)(qrow + 32 + l4 * 8);
  }

  f32x4 oacc[4];
#pragma unroll
  for (int i = 0; i < 4; ++i) oacc[i] = zero4();
  float lrow[4] = {0.f, 0.f, 0.f, 0.f};   // per-lane partial denominators

  // K/V stage: 1 K + 1 V gload_lds per thread
  auto STAGE_KV = [&](int kt, int sb) {
    int row = t >> 3;
    int slot = (t & 7) ^ (row & 7);
    gload_lds16(Kp + (size_t)(kt * 64 + row) * DH_ + slot * 8, (char*)Ks[sb] + w * 1024);
    gload_lds16(Vp + (size_t)row * S_ + kt * 64 + slot * 8, (char*)Vs[sb] + w * 1024);
  };

  uint4 pbc, pbn;
  float mcur[2], mnxt[2];

  // ---- prologue: stage tile 0 (K,V), pb chunk 0, mask regs ----
  STAGE_KV(0, 0);
  pbc = *(const uint4*)pbp;
#pragma unroll
  for (int kf = 0; kf < 2; ++kf) mcur[kf] = maskp[kc0 + kf * 16 + l15];
  __syncthreads();

  for (int kt = 0; kt < S_ / 64; ++kt) {
    // ---- phase 1: issue next tile's stages + pb/mask prefetch ----
    if (kt + 1 < S_ / 64) {
      STAGE_KV(kt + 1, (kt + 1) & 1);
      pbn = *(const uint4*)(pbp + (size_t)(kt + 1) * 4096);
#pragma unroll
      for (int kf = 0; kf < 2; ++kf)
        mnxt[kf] = maskp[(kt + 1) * 64 + kc0 + kf * 16 + l15];
    }

    // ---- phase 2: compute on tile kt ----
    const u16* Kc = Ks[kt & 1];
    const u16* Vc = Vs[kt & 1];

    // S = Q K^T (scale pre-folded into Q)
    f32x4 sf[2];
#pragma unroll
    for (int kf = 0; kf < 2; ++kf) {
      int row = kc0 + kf * 16 + l15;
      bf16x8 kb0 = *(const bf16x8*)((const char*)Kc + row * 128 +
                                    ((l4 << 4) ^ ((row & 7) << 4)));
      bf16x8 kb1 = *(const bf16x8*)((const char*)Kc + row * 128 +
                                    ((64 + (l4 << 4)) ^ ((row & 7) << 4)));
      f32x4 s0 = zero4();
      s0 = mfma16(qf0, kb0, s0);
      s0 = mfma16(qf1, kb1, s0);
      sf[kf] = s0;
    }

    // p = exp(s + mask) * pb; accumulate per-lane denominators
    {
      const u16* ps = (const u16*)&pbc;
#pragma unroll
      for (int kf = 0; kf < 2; ++kf) {
#pragma unroll
        for (int r = 0; r < 4; ++r) {
          float pbf = __uint_as_float((unsigned)ps[kf * 4 + r] << 16);
          float p = __expf(sf[kf][r] + mcur[kf]) * pbf;
          sf[kf][r] = p;
          lrow[r] += p;
        }
      }
    }

    // P -> bf16, wave-private repack (own 16x32 block only)
#pragma unroll
    for (int r = 0; r < 4; ++r)
#pragma unroll
      for (int kf = 0; kf < 2; ++kf)
        Ps[qg][(l4 << 2) + r][kc0 + kf * 16 + l15] = f2bf(sf[kf][r]);

    bf16x8 pa = *(const bf16x8*)&Ps[qg][l15][kc0 + l4 * 8];

    // O_partial += P V over this wave's k-half
#pragma unroll
    for (int df = 0; df < 4; ++df) {
      int row = df * 16 + l15;
      bf16x8 vb = *(const bf16x8*)((const char*)Vc + row * 128 +
                                   ((kg * 64 + (l4 << 4)) ^ ((row & 7) << 4)));
      oacc[df] = mfma16(pa, vb, oacc[df]);
    }

    // ---- single barrier: drains stage vmcnt, orders LDS buffer reuse ----
    __syncthreads();
    pbc = pbn;
    mcur[0] = mnxt[0]; mcur[1] = mnxt[1];
  }

  // ---- epilogue: combine k-split partials, normalize, write bf16 ----
#pragma unroll
  for (int r = 0; r < 4; ++r) {
#pragma unroll
    for (int o = 1; o < 16; o <<= 1) lrow[r] += __shfl_xor(lrow[r], o, 64);
  }
  if (l15 == 0) {
#pragma unroll
    for (int r = 0; r < 4; ++r) Lsh[qg][kg][(l4 << 2) + r] = lrow[r];
  }
  if (kg == 1) {
#pragma unroll
    for (int r = 0; r < 4; ++r)
#pragma unroll
      for (int df = 0; df < 4; ++df)
        Osh[qg][(l4 << 2) + r][df * 16 + l15] = oacc[df][r];
  }
  __syncthreads();
  if (kg == 0) {
#pragma unroll
    for (int r = 0; r < 4; ++r) {
      int rr = (l4 << 2) + r;
      float inv = 1.0f / (Lsh[qg][0][rr] + Lsh[qg][1][rr]);
      int q = q0 + qg * 16 + rr;
      size_t base = ((size_t)b * S_ + q) * D_ + h * DH_ + l15;
#pragma unroll
      for (int df = 0; df < 4; ++df)
        Cb[base + df * 16] = f2bf((oacc[df][r] + Osh[qg][rr][df * 16 + l15]) * inv);
    }
  }
}

// ---------------- residual + LayerNorm ----------------
__global__ __launch_bounds__(192) void ln_kernel(const float* __restrict__ O,
                                                 const float* __restrict__ hid,
                                                 const float* __restrict__ lw,
                                                 const float* __restrict__ lb,
                                                 float* __restrict__ out) {
  int row = blockIdx.x, t = threadIdx.x;
  size_t base = (size_t)row * D_;
  f32x4 x = *(const f32x4*)(O + base + t * 4);
  f32x4 hh = *(const f32x4*)(hid + base + t * 4);
  x = x + hh;
  float s = x[0] + x[1] + x[2] + x[3];
  float s2 = x[0] * x[0] + x[1] * x[1] + x[2] * x[2] + x[3] * x[3];
#pragma unroll
  for (int o = 1; o < 64; o <<= 1) {
    s += __shfl_xor(s, o, 64);
    s2 += __shfl_xor(s2, o, 64);
  }
  __shared__ float rs[3], rs2[3];
  int w = t >> 6, lane = t & 63;
  if (lane == 0) { rs[w] = s; rs2[w] = s2; }
  __syncthreads();
  s = rs[0] + rs[1] + rs[2];
  s2 = rs2[0] + rs2[1] + rs2[2];
  float mu = s * (1.0f / 768.0f);
  float var = s2 * (1.0f / 768.0f) - mu * mu;
  float rstd = rsqrtf(var + 1e-12f);
  f32x4 w4 = *(const f32x4*)(lw + t * 4);
  f32x4 b4 = *(const f32x4*)(lb + t * 4);
  f32x4 y = (x - mu) * rstd * w4 + b4;
  *(f32x4*)(out + base + t * 4) = y;
}

// ---------------- launcher ----------------
extern "C" void kernel_launch(void* const* d_in, const int* in_sizes, int n_in,
                              void* d_out, int out_size, void* d_ws, size_t ws_size,
                              hipStream_t stream) {
  const float* hid  = (const float*)d_in[0];
  const float* mask = (const float*)d_in[1];
  const float* bias = (const float*)d_in[2];
  const float* qw = (const float*)d_in[3];
  const float* qb = (const float*)d_in[4];
  const float* kw = (const float*)d_in[5];
  const float* kb = (const float*)d_in[6];
  const float* vw = (const float*)d_in[7];
  const float* vb = (const float*)d_in[8];
  const float* ow = (const float*)d_in[9];
  const float* ob = (const float*)d_in[10];
  const float* lnw = (const float*)d_in[11];
  const float* lnb = (const float*)d_in[12];

  char* ws = (char*)d_ws;
  const size_t SZ6 = (size_t)B_ * S_ * D_ * 2;       // 6291456
  const size_t SZW = (size_t)4 * D_ * D_ * 2;        // 4718592
  // layout (overlays noted):
  //  [0]        Hb (gemm0 input)  -- later reused as Cb (attn output)
  //  [o1]       Wb
  //  [o2..o5]   Qb, Kb, Vt, Vtmp
  //  [o6]       pb (100.7 MB, prepack out; dead after attn) -- Of overlays pb[0:12.6MB]
  u16* Hb = (u16*)ws;
  u16* Cb = (u16*)ws;                                 // alias: Hb dead after gemm0
  u16* Wb = (u16*)(ws + SZ6);
  u16* Qb = (u16*)(ws + SZ6 + SZW);
  u16* Kb = (u16*)(ws + 2 * SZ6 + SZW);
  u16* Vt = (u16*)(ws + 3 * SZ6 + SZW);
  u16* Vtmp = (u16*)(ws + 4 * SZ6 + SZW);
  u16* pbuf = (u16*)(ws + 5 * SZ6 + SZW);             // 100663296 B
  float* Of = (float*)(ws + 5 * SZ6 + SZW);           // alias: pb dead after attn

  cvt_kernel<<<2048, 256, 0, stream>>>(hid, qw, kw, vw, ow, Hb, Wb);

  prepack_kernel<<<6144, 256, 0, stream>>>(bias, pbuf);

  gemm_kernel<<<dim3(18, 32), 256, 0, stream>>>(
      Hb, Wb, qb, kb, vb, Qb, Kb, Vtmp, nullptr, nullptr, 0);

  vtrans_kernel<<<dim3(S_ / 64, B_ * H_), 256, 0, stream>>>(Vtmp, Vt);

  attn_kernel<<<dim3(S_ / 64, H_, B_), 512, 0, stream>>>(Qb, Kb, Vt, pbuf, mask, Cb);

  gemm_kernel<<<dim3(6, 32), 256, 0, stream>>>(
      Cb, Wb + (size_t)3 * D_ * D_, nullptr, nullptr, nullptr,
      nullptr, nullptr, nullptr, Of, ob, 1);

  ln_kernel<<<B_ * S_, 192, 0, stream>>>(Of, hid, lnw, lnb, (float*)d_out);
}